// Round 7
// baseline (369.104 us; speedup 1.0000x reference)
//
#include <hip/hip_runtime.h>

// ---------------------------------------------------------------------------
// EdgeLLMAttentionTRTNative: out = X @ (s*Wo@Wq)^T + kv_cache passthrough.
// Round 7: fix the LDS-read/MFMA ratio. Per-wave output 128x64 (m201 shape,
// ab/(a+b)=2.67 > 2.5 threshold) so LDS fragment reads fit under MFMA.
// BM=BN=256, BK=32, 8 waves 2Mx4N, acc[8][4]; 4-slot LDS ring (128KB),
// stage tile T+2 (A@Ph1, B@Ph2; stage slot != compute/readahead slots);
// 2 phases/tile x 16 MFMA; vmcnt(2) at tile boundary; chunk-XOR swizzle.
// ---------------------------------------------------------------------------

typedef __attribute__((ext_vector_type(8))) __bf16 bf16x8;
typedef __attribute__((ext_vector_type(4))) float f32x4;

__device__ __forceinline__ unsigned short f2bf(float f) {
  union { float f; unsigned u; } v; v.f = f;
  unsigned r = v.u + 0x7fffu + ((v.u >> 16) & 1u);   // round-to-nearest-even
  return (unsigned short)(r >> 16);
}

__global__ void cast_f32_to_bf16(const float4* __restrict__ in,
                                 ushort4* __restrict__ out, int n4) {
  int i = blockIdx.x * blockDim.x + threadIdx.x;
  int stride = gridDim.x * blockDim.x;
  for (; i < n4; i += stride) {
    float4 v = in[i];
    ushort4 o;
    o.x = f2bf(v.x); o.y = f2bf(v.y); o.z = f2bf(v.z); o.w = f2bf(v.w);
    out[i] = o;
  }
}

// out (C x R, bf16) = transpose of in (R x C, fp32)
__global__ void transpose_cast(const float* __restrict__ in,
                               ushort* __restrict__ out, int R, int C) {
  __shared__ float tile[32][33];
  const int tc = blockIdx.x * 32;
  const int tr = blockIdx.y * 32;
  const int lx = threadIdx.x & 31;
  const int ly = threadIdx.x >> 5;
#pragma unroll
  for (int i = 0; i < 32; i += 8)
    tile[ly + i][lx] = in[(size_t)(tr + ly + i) * C + (tc + lx)];
  __syncthreads();
#pragma unroll
  for (int i = 0; i < 32; i += 8)
    out[(size_t)(tc + ly + i) * R + (tr + lx)] = f2bf(tile[lx][ly + i]);
}

typedef const __attribute__((address_space(1))) void* gptr_t;
typedef __attribute__((address_space(3))) void* lptr_t;

__device__ __forceinline__ void gload16(const void* g, void* l) {
  __builtin_amdgcn_global_load_lds((gptr_t)g, (lptr_t)l, 16, 0, 0);
}

#define BAR   do { asm volatile("" ::: "memory"); __builtin_amdgcn_s_barrier(); asm volatile("" ::: "memory"); } while (0)
#define LGKM0 asm volatile("s_waitcnt lgkmcnt(0)" ::: "memory")
#define VM(n) asm volatile("s_waitcnt vmcnt(" #n ")" ::: "memory")

// ---------------------------------------------------------------------------
// GEMM: C = A(MxK) * B(NxK)^T, bf16 in, f32 or scaled-bf16 out.
// BM=BN=256, BK=32; 8 waves 2Mx4N, per-wave 128x64, acc[8][4] (128 VGPR).
// LDS: 4 slots x (A 256x32 16KB + B 256x32 16KB) = 128KB ring.
// Swizzle: 16B chunk c of row r stored at c^((r>>1)&3), via pre-swizzled
// global source (rule 21) + XOR'd read offset. Proven in round 3 (0 confl).
// Schedule per tile T (slot s=T&3; read-ahead slot s1=(T+1)&3; stage slot
// (T+2)&3 — all distinct, so staging never races reads):
//  Ph1: read Af1 (A mh1, 4 b128, slot s); stage A(T+2) [2 vm];
//       BAR; LGKM0; 16 MFMA (Af0 x Bcur); vmcnt(2|0); BAR.
//       vmcnt(2): queue = [B(T+1) 2, A(T+2) 2] -> B(T+1) landed; with A(T+1)
//       older => tile T+1 fully in LDS before any wave's Ph2 read-ahead.
//  Ph2: read Af0'/Bnext (8 b128, slot s1); stage B(T+2) [2 vm];
//       BAR; LGKM0; 16 MFMA (Af1 x Bcur); BAR.
// Per-CU per tile: MFMA 8*32*4.85 = 1242 cyc vs LDS reads 12*8KB/85 = 1156
// cyc -> MFMA-bound (rounds 3/5/6 had this inverted).
// ---------------------------------------------------------------------------
template <int OUT_BF16>
__global__ __launch_bounds__(512, 2)
void gemm_p(const ushort* __restrict__ A, const ushort* __restrict__ B,
            void* __restrict__ Cv, int M, int N, int K, float scale) {
  __shared__ __align__(16) char smem[131072];

  const int t    = threadIdx.x;
  const int w    = t >> 6;
  const int lane = t & 63;
  const int wr   = w >> 2;             // 0..1  (M: 128 rows each)
  const int wc   = w & 3;              // 0..3  (N: 64 cols each)
  const int fr   = lane & 15;
  const int g    = lane >> 4;          // 0..3

  // XCD-aware bijective swizzle: nwg % 8 == 0 by construction.
  const int nwg = gridDim.x;
  const int cpx = nwg >> 3;
  const int wg  = (blockIdx.x & 7) * cpx + (blockIdx.x >> 3);
  const int nbx = N >> 8;
  const int bx  = wg % nbx, by = wg / nbx;
  const int rowBase = by * 256, colBase = bx * 256;

  // Staging (per 8KB call: 128 rows x 64B, thread t -> row t>>2, chunk t&3;
  // stored chunk holds logical chunk (t&3)^((t>>3)&3) since (row>>1)&3=(t>>3)&3).
  const int srow = t >> 2;                              // 0..127
  const int scol = ((t & 3) ^ ((t >> 3) & 3)) << 3;     // pre-swizzled col
  const ushort* Ag = A + (size_t)(rowBase + srow) * K + scol;
  const ushort* Bg = B + (size_t)(colBase + srow) * K + scol;
  const int wofs = w << 10;                             // wave LDS byte offset

#define SLOT(T) (((T) & 3) * 32768)
#define STAGE_A(kt) do { char* d_ = smem + SLOT(kt) + wofs;            \
    const ushort* s_ = Ag + (size_t)(kt) * 32;                         \
    gload16(s_, d_); gload16(s_ + (size_t)128 * K, d_ + 8192); } while (0)
#define STAGE_B(kt) do { char* d_ = smem + SLOT(kt) + 16384 + wofs;    \
    const ushort* s_ = Bg + (size_t)(kt) * 32;                         \
    gload16(s_, d_); gload16(s_ + (size_t)128 * K, d_ + 8192); } while (0)

  // Fragment reads: row stride 64B; logical chunk g stored at g^((fr>>1)&3).
  const int cs   = (g ^ ((fr >> 1) & 3)) << 4;
  const int aOff = (wr * 128 + fr) * 64 + cs;           // + MH*4096 + m*1024
  const int bOff = 16384 + (wc * 64 + fr) * 64 + cs;    // + n*1024

#define READ_A(dst, so, MH) do {                                       \
    const char* p_ = smem + (so) + aOff + (MH) * 4096;                 \
    dst[0] = *(const bf16x8*)(p_);                                     \
    dst[1] = *(const bf16x8*)(p_ + 1024);                              \
    dst[2] = *(const bf16x8*)(p_ + 2048);                              \
    dst[3] = *(const bf16x8*)(p_ + 3072); } while (0)
#define READ_B(dst, so) do {                                           \
    const char* p_ = smem + (so) + bOff;                               \
    dst[0] = *(const bf16x8*)(p_);                                     \
    dst[1] = *(const bf16x8*)(p_ + 1024);                              \
    dst[2] = *(const bf16x8*)(p_ + 2048);                              \
    dst[3] = *(const bf16x8*)(p_ + 3072); } while (0)
#define MFMA16(MH, A4, B4) do {                                        \
    _Pragma("unroll") for (int mi_ = 0; mi_ < 4; ++mi_)                \
    _Pragma("unroll") for (int ni_ = 0; ni_ < 4; ++ni_)                \
      acc[(MH) * 4 + mi_][ni_] = __builtin_amdgcn_mfma_f32_16x16x32_bf16( \
          A4[mi_], B4[ni_], acc[(MH) * 4 + mi_][ni_], 0, 0, 0); } while (0)

  f32x4 acc[8][4];
#pragma unroll
  for (int m = 0; m < 8; ++m)
#pragma unroll
    for (int n = 0; n < 4; ++n)
      acc[m][n] = f32x4{0.f, 0.f, 0.f, 0.f};

  bf16x8 Af0[4], Af1[4], Bp[4], Bq[4];

  const int nt = K >> 5;               // 96 (even)

  // Prologue: stage tiles 0,1; wait tile 0 (allow tile 1 in flight);
  // pre-read Af0/Bp of tile 0.
  STAGE_A(0); STAGE_B(0);
  STAGE_A(1); STAGE_B(1);
  VM(4);
  BAR;
  READ_A(Af0, SLOT(0), 0);
  READ_B(Bp, SLOT(0));

#define TILE_BODY(T, BC, BN_) do {                                            \
    const int so_  = SLOT(T);                                                 \
    const int so1_ = SLOT((T) + 1);                                           \
    const bool stg_ = (T) + 2 < nt;                                           \
    /* Ph1 */                                                                 \
    READ_A(Af1, so_, 1);                                                      \
    if (stg_) STAGE_A((T) + 2);                                               \
    BAR; LGKM0;                                                               \
    __builtin_amdgcn_s_setprio(1); MFMA16(0, Af0, BC); __builtin_amdgcn_s_setprio(0); \
    if ((T) < nt - 2) { VM(2); } else { VM(0); }                              \
    BAR;                                                                      \
    /* Ph2 */                                                                 \
    if ((T) + 1 < nt) { READ_A(Af0, so1_, 0); READ_B(BN_, so1_); }            \
    if (stg_) STAGE_B((T) + 2);                                               \
    BAR; LGKM0;                                                               \
    __builtin_amdgcn_s_setprio(1); MFMA16(1, Af1, BC); __builtin_amdgcn_s_setprio(0); \
    BAR;                                                                      \
  } while (0)

  for (int T = 0; T < nt; T += 2) {
    TILE_BODY(T, Bp, Bq);
    TILE_BODY(T + 1, Bq, Bp);
  }

#undef TILE_BODY
#undef STAGE_A
#undef STAGE_B
#undef READ_A
#undef READ_B
#undef MFMA16
#undef SLOT

  // C/D layout: col = lane&15, row = (lane>>4)*4 + i
  const int orow = rowBase + wr * 128 + (g << 2);
  const int ocol = colBase + wc * 64 + fr;
#pragma unroll
  for (int mi = 0; mi < 8; ++mi)
#pragma unroll
    for (int ni = 0; ni < 4; ++ni)
#pragma unroll
      for (int i = 0; i < 4; ++i) {
        const size_t idx = (size_t)(orow + mi * 16 + i) * N + (ocol + ni * 16);
        float v = acc[mi][ni][i] * scale;
        if (OUT_BF16) ((ushort*)Cv)[idx] = f2bf(v);
        else          ((float*)Cv)[idx]  = v;
      }
}

extern "C" void kernel_launch(void* const* d_in, const int* in_sizes, int n_in,
                              void* d_out, int out_size, void* d_ws, size_t ws_size,
                              hipStream_t stream) {
  const float* hs = (const float*)d_in[0];   // (4,2048,3072)
  const float* kv = (const float*)d_in[4];   // (4,2,8,4096,128)
  const float* Wq = (const float*)d_in[5];   // (3072,3072) (d,h)
  const float* Wo = (const float*)d_in[8];   // (3072,3072) (o,d)

  const int M = 8192, H = 3072;
  const int OUT_ELEMS = M * H;

  float* out = (float*)d_out;

  ushort* Xb   = (ushort*)d_ws;
  ushort* Wob  = Xb + (size_t)M * H;
  ushort* WqTb = Wob + (size_t)H * H;
  // Fused weight W = s*Wo@Wq (bf16) in the kv-tail of d_out; overwritten by
  // the kv_cache copy afterwards (stream-ordered).
  ushort* Wb   = (ushort*)(out + OUT_ELEMS);

  cast_f32_to_bf16<<<2048, 256, 0, stream>>>((const float4*)hs, (ushort4*)Xb, (M * H) / 4);
  cast_f32_to_bf16<<<1024, 256, 0, stream>>>((const float4*)Wo, (ushort4*)Wob, (H * H) / 4);
  transpose_cast<<<dim3(H / 32, H / 32), 256, 0, stream>>>(Wq, WqTb, H, H);

  const float qk_scale = 0.08838834764831845f;  // 128^-0.5
  // W[o,h] = s * sum_d Wo[o,d] * Wq[d,h]   (grid 12*12 = 144, %8==0)
  gemm_p<1><<<(H / 256) * (H / 256), 512, 0, stream>>>(Wob, WqTb, (void*)Wb, H, H, H, qk_scale);
  // out[m,o] = sum_h X[m,h] * W[o,h]       (grid 32*12 = 384, %8==0)
  gemm_p<0><<<(M / 256) * (H / 256), 512, 0, stream>>>(Xb, Wb, (void*)out, M, H, H, 1.0f);

  hipMemcpyAsync(out + OUT_ELEMS, kv, (size_t)in_sizes[4] * sizeof(float),
                 hipMemcpyDeviceToDevice, stream);
}